// Round 6
// baseline (328.274 us; speedup 1.0000x reference)
//
#include <hip/hip_runtime.h>
#include <stdint.h>

#define BB 1024
#define NN 400
#define EE 128
#define DD 128
#define NSLOT 64
#define GTS2 232             // GT row stride in shorts (116 dwords == 20 mod 32 -> 2-way banks, free)
#define KH0 224              // k-half 0: slots 0..223 (7 MFMA steps)
#define KH1 192              // k-half 1: slots 0..191 (6 steps; real k 224..399, rest zero)

typedef float f32x4 __attribute__((ext_vector_type(4)));
typedef short bf16x8 __attribute__((ext_vector_type(8)));

__device__ __forceinline__ short f2bf(float f) {
    uint32_t u = __builtin_bit_cast(uint32_t, f);
    u += 0x7fffu + ((u >> 16) & 1u);
    return (short)(u >> 16);
}

__device__ __forceinline__ float bf2f(short s) {
    return __builtin_bit_cast(float, (uint32_t)((uint16_t)s) << 16);
}

__device__ __forceinline__ bf16x8 cvt8(const f32x4 a, const f32x4 b) {
    bf16x8 r;
    r[0] = f2bf(a[0]); r[1] = f2bf(a[1]); r[2] = f2bf(a[2]); r[3] = f2bf(a[3]);
    r[4] = f2bf(b[0]); r[5] = f2bf(b[1]); r[6] = f2bf(b[2]); r[7] = f2bf(b[3]);
    return r;
}

// K1: one 512-thread block (8 waves) per b. LDS 58KB -> 2 blocks/CU co-resident.
//   GT staged in two k-halves over one [128][232] region; A via 2-deep raw-f32 ring.
//   Wave w owns 32 P-rows (w<4: S rows w*32..; w>=4: T rows (w-4)*32..).
//   Stage 2 in two passes through 32KB Ps (S then T), W1 direct from global (L2).
__global__ __launch_bounds__(512, 4)
void k1_gemm(const float* __restrict__ gout, const float* __restrict__ ss,
             const float* __restrict__ es, const float* __restrict__ W1,
             const float* __restrict__ b1, unsigned short* __restrict__ h,
             float* __restrict__ stats1)
{
    __shared__ short lds[29696];           // 58 KB
    short* GT = lds;                       // [128][232] bf16 (phase 0/1)
    short* Ps = lds;                       // [128][128] bf16 (phase 2, aliases GT)

    const int b   = blockIdx.x;
    const int t   = threadIdx.x;
    const int w   = t >> 6;                // wave 0..7
    const int l   = t & 63;
    const int l15 = l & 15;
    const int l4  = l >> 4;                // 0..3
    const int kkoff = l4 * 8;

    // A row bases: wave w<4 -> ss rows (w*32..), w>=4 -> es rows ((w-4)*32..)
    const float* abase0 = ((w < 4) ? ss : es) + ((size_t)b * EE + (w & 3) * 32 + l15) * NN;
    const float* abase1 = abase0 + 16 * NN;

    // ---- pre-issue A ring for K-steps 0,1 (raw f32; cvt deferred) ----
    f32x4 c00 = *(const f32x4*)(abase0 + kkoff);
    f32x4 c01 = *(const f32x4*)(abase0 + kkoff + 4);
    f32x4 c10 = *(const f32x4*)(abase1 + kkoff);
    f32x4 c11 = *(const f32x4*)(abase1 + kkoff + 4);
    f32x4 n00 = *(const f32x4*)(abase0 + 32 + kkoff);
    f32x4 n01 = *(const f32x4*)(abase0 + 32 + kkoff + 4);
    f32x4 n10 = *(const f32x4*)(abase1 + 32 + kkoff);
    f32x4 n11 = *(const f32x4*)(abase1 + 32 + kkoff + 4);

    // ---- GT staging (k-quads packed, b64 writes) ----
    const float* gb = gout + (size_t)b * NN * DD + (t & 127);
    auto stage = [&](int koff, int nq) {
        const int qb = t >> 7;             // 0..3
        short* row = &GT[(t & 127) * GTS2];
        for (int q = qb; q < nq; q += 4) {
            int kg = koff + 4 * q;
            float v0 = (kg     < NN) ? gb[(size_t)(kg)     * DD] : 0.f;
            float v1 = (kg + 1 < NN) ? gb[(size_t)(kg + 1) * DD] : 0.f;
            float v2 = (kg + 2 < NN) ? gb[(size_t)(kg + 2) * DD] : 0.f;
            float v3 = (kg + 3 < NN) ? gb[(size_t)(kg + 3) * DD] : 0.f;
            uint32_t lo = (uint32_t)(uint16_t)f2bf(v0) | ((uint32_t)(uint16_t)f2bf(v1) << 16);
            uint32_t hi = (uint32_t)(uint16_t)f2bf(v2) | ((uint32_t)(uint16_t)f2bf(v3) << 16);
            *(uint64_t*)&row[4 * q] = ((uint64_t)hi << 32) | lo;
        }
    };

    stage(0, KH0 / 4);                     // phase 0a: k 0..223
    __syncthreads();

    // ---- phase 1: P(32 rows x 128 d per wave), GT re-staged at s==7 ----
    f32x4 acc[2][8];
#pragma unroll
    for (int i = 0; i < 2; ++i)
#pragma unroll
        for (int j = 0; j < 8; ++j) acc[i][j] = f32x4{0.f, 0.f, 0.f, 0.f};

#pragma unroll
    for (int s = 0; s < 13; ++s) {
        if (s == 7) {
            __syncthreads();               // all waves done reading GTa
            stage(KH0, KH1 / 4);           // phase 0b: k 224..415 (zeros past 399)
            __syncthreads();
        }
        bf16x8 a0 = cvt8(c00, c01);
        bf16x8 a1 = cvt8(c10, c11);
        c00 = n00; c01 = n01; c10 = n10; c11 = n11;
        const int sn = s + 2;
        if (sn < 12) {
            n00 = *(const f32x4*)(abase0 + sn * 32 + kkoff);
            n01 = *(const f32x4*)(abase0 + sn * 32 + kkoff + 4);
            n10 = *(const f32x4*)(abase1 + sn * 32 + kkoff);
            n11 = *(const f32x4*)(abase1 + sn * 32 + kkoff + 4);
        } else if (sn == 12) {
            int kk = 384 + kkoff;
            n00 = n01 = n10 = n11 = f32x4{0.f, 0.f, 0.f, 0.f};
            if (kk < NN) {
                n00 = *(const f32x4*)(abase0 + kk);
                n01 = *(const f32x4*)(abase0 + kk + 4);
                n10 = *(const f32x4*)(abase1 + kk);
                n11 = *(const f32x4*)(abase1 + kk + 4);
            }
        }
        const int k0 = (s < 7 ? s * 32 : (s - 7) * 32) + kkoff;
#pragma unroll
        for (int cg = 0; cg < 4; ++cg) {
            bf16x8 gf0 = *(const bf16x8*)&GT[(cg * 32 + l15) * GTS2 + k0];
            bf16x8 gf1 = *(const bf16x8*)&GT[(cg * 32 + 16 + l15) * GTS2 + k0];
            acc[0][2 * cg]     = __builtin_amdgcn_mfma_f32_16x16x32_bf16(a0, gf0, acc[0][2 * cg], 0, 0, 0);
            acc[1][2 * cg]     = __builtin_amdgcn_mfma_f32_16x16x32_bf16(a1, gf0, acc[1][2 * cg], 0, 0, 0);
            acc[0][2 * cg + 1] = __builtin_amdgcn_mfma_f32_16x16x32_bf16(a0, gf1, acc[0][2 * cg + 1], 0, 0, 0);
            acc[1][2 * cg + 1] = __builtin_amdgcn_mfma_f32_16x16x32_bf16(a1, gf1, acc[1][2 * cg + 1], 0, 0, 0);
        }
    }
    __syncthreads();                       // GT dead; Ps region live

    // ---- stage 2, two passes: h += X_half @ W1_half^T ----
    const int mt = w >> 1;                 // e-tile (32 rows)
    const int jh = w & 1;                  // j-half (64 cols)
    f32x4 acc2[2][4];
#pragma unroll
    for (int i = 0; i < 2; ++i)
#pragma unroll
        for (int j = 0; j < 4; ++j) acc2[i][j] = f32x4{0.f, 0.f, 0.f, 0.f};

#pragma unroll
    for (int pass = 0; pass < 2; ++pass) {
        // write this pass's P half (S rows from waves 0-3, T rows from waves 4-7)
        if ((pass == 0) == (w < 4)) {
#pragma unroll
            for (int rf = 0; rf < 2; ++rf)
#pragma unroll
                for (int cf = 0; cf < 8; ++cf)
#pragma unroll
                    for (int r = 0; r < 4; ++r) {
                        int row = (w & 3) * 32 + rf * 16 + l4 * 4 + r;
                        int col = cf * 16 + l15;
                        Ps[row * 128 + (((col >> 3) ^ (row & 7)) << 3) + (col & 7)] = f2bf(acc[rf][cf][r]);
                    }
        }
        __syncthreads();
#pragma unroll
        for (int kf = 0; kf < 4; ++kf) {
            bf16x8 xf[2];
#pragma unroll
            for (int rf2 = 0; rf2 < 2; ++rf2) {
                int row = mt * 32 + rf2 * 16 + l15;
                int cb  = kf * 4 + l4;
                xf[rf2] = *(const bf16x8*)&Ps[row * 128 + ((cb ^ (row & 7)) << 3)];
            }
#pragma unroll
            for (int cf = 0; cf < 4; ++cf) {
                int j = jh * 64 + cf * 16 + l15;
                const float* wp = W1 + (size_t)j * 256 + pass * 128 + kf * 32 + l4 * 8;
                bf16x8 wf = cvt8(*(const f32x4*)wp, *(const f32x4*)(wp + 4));
                acc2[0][cf] = __builtin_amdgcn_mfma_f32_16x16x32_bf16(xf[0], wf, acc2[0][cf], 0, 0, 0);
                acc2[1][cf] = __builtin_amdgcn_mfma_f32_16x16x32_bf16(xf[1], wf, acc2[1][cf], 0, 0, 0);
            }
        }
        __syncthreads();                   // pass reads done (next pass overwrites Ps)
    }

    // ---- epilogue: bias, store h (bf16), BN1 stats ----
    float* red = (float*)lds;              // 512+512 floats (Ps dead)
    float s_r[2][4] = {{0.f,0.f,0.f,0.f},{0.f,0.f,0.f,0.f}};
    float q_r[2][4] = {{0.f,0.f,0.f,0.f},{0.f,0.f,0.f,0.f}};
#pragma unroll
    for (int rf2 = 0; rf2 < 2; ++rf2)
#pragma unroll
        for (int cf = 0; cf < 4; ++cf) {
            float bv = b1[jh * 64 + cf * 16 + l15];
            f32x4 v = acc2[rf2][cf] + bv;
#pragma unroll
            for (int r = 0; r < 4; ++r) {
                int e = mt * 32 + rf2 * 16 + l4 * 4 + r;
                h[((size_t)b * EE + e) * DD + jh * 64 + cf * 16 + l15] = (unsigned short)f2bf(v[r]);
                s_r[rf2][r] += v[r];
                q_r[rf2][r] += v[r] * v[r];
            }
        }
#pragma unroll
    for (int rf2 = 0; rf2 < 2; ++rf2)
#pragma unroll
        for (int r = 0; r < 4; ++r) {
            float s = s_r[rf2][r], q = q_r[rf2][r];
            s += __shfl_xor(s, 1); s += __shfl_xor(s, 2); s += __shfl_xor(s, 4); s += __shfl_xor(s, 8);
            q += __shfl_xor(q, 1); q += __shfl_xor(q, 2); q += __shfl_xor(q, 4); q += __shfl_xor(q, 8);
            if (l15 == 0) {
                int e = mt * 32 + rf2 * 16 + l4 * 4 + r;
                red[(e << 1) | jh]       = s;
                red[512 + ((e << 1) | jh)] = q;
            }
        }
    __syncthreads();
    if (t < 128) {
        float s = red[2 * t] + red[2 * t + 1];
        float q = red[512 + 2 * t] + red[512 + 2 * t + 1];
        int slot = b & (NSLOT - 1);
        atomicAdd(&stats1[slot * 256 + t], s);
        atomicAdd(&stats1[slot * 256 + 128 + t], q);
    }
}

// K3: per b: finalize BN1, normalize+relu h(bf16) -> bf16 LDS,
// h2 = X @ W2^T + b2 -> written IN-PLACE over h (bf16), BN2 stats.
__global__ __launch_bounds__(256, 4)
void k3_gemm(unsigned short* h, const float* __restrict__ W2,
             const float* __restrict__ b2, const float* __restrict__ g1,
             const float* __restrict__ bt1,
             const float* __restrict__ stats1, float* __restrict__ stats2)
{
    __shared__ short Xs[128 * 128];
    __shared__ float sc[128];
    __shared__ float sh[128];
    const int b   = blockIdx.x;
    const int t   = threadIdx.x;
    const int w   = t >> 6;
    const int l15 = t & 15;
    const int l4  = (t >> 4) & 3;

    if (t < 128) {
        float sm = 0.f, sq = 0.f;
#pragma unroll 8
        for (int sl = 0; sl < NSLOT; ++sl) {
            sm += stats1[sl * 256 + t];
            sq += stats1[sl * 256 + 128 + t];
        }
        const float inv_n = 1.0f / (1024.0f * 128.0f);
        float m    = sm * inv_n;
        float var  = sq * inv_n - m * m;
        float rstd = rsqrtf(var + 1e-5f);
        float s    = rstd * g1[t];
        sc[t] = s;
        sh[t] = bt1[t] - m * s;
    }
    __syncthreads();

    {
        const int c8 = t & 15;
        const int eb = t >> 4;
#pragma unroll
        for (int p = 0; p < 8; ++p) {
            int e = eb + 16 * p;
            bf16x8 v8 = *(const bf16x8*)&h[((size_t)b * EE + e) * DD + c8 * 8];
            float s = sc[e], s0 = sh[e];
            bf16x8 o;
#pragma unroll
            for (int i = 0; i < 8; ++i)
                o[i] = f2bf(fmaxf(fmaf(bf2f(v8[i]), s, s0), 0.0f));
            *(bf16x8*)&Xs[e * 128 + ((c8 ^ (e & 7)) << 3)] = o;
        }
    }
    __syncthreads();

    f32x4 acc[8][2];
#pragma unroll
    for (int i = 0; i < 8; ++i) {
        acc[i][0] = f32x4{0.f, 0.f, 0.f, 0.f};
        acc[i][1] = f32x4{0.f, 0.f, 0.f, 0.f};
    }
#pragma unroll
    for (int kf = 0; kf < 4; ++kf) {
        const int k0 = kf * 32;
        const int cb = (k0 >> 3) + l4;
        bf16x8 af[8];
#pragma unroll
        for (int rf = 0; rf < 8; ++rf) {
            int row = rf * 16 + l15;
            af[rf] = *(const bf16x8*)&Xs[row * 128 + ((cb ^ (row & 7)) * 8)];
        }
#pragma unroll
        for (int cf = 0; cf < 2; ++cf) {
            int j = w * 32 + cf * 16 + l15;
            const float* wp = W2 + (size_t)j * 128 + k0 + l4 * 8;
            bf16x8 bfr = cvt8(*(const f32x4*)wp, *(const f32x4*)(wp + 4));
#pragma unroll
            for (int rf = 0; rf < 8; ++rf)
                acc[rf][cf] = __builtin_amdgcn_mfma_f32_16x16x32_bf16(af[rf], bfr, acc[rf][cf], 0, 0, 0);
        }
    }

    __syncthreads();
    float* red = (float*)Xs;
    const float bj0 = b2[w * 32 + l15];
    const float bj1 = b2[w * 32 + 16 + l15];
    const int j0 = w * 32 + l15;
#pragma unroll
    for (int rf = 0; rf < 8; ++rf) {
        f32x4 v0 = acc[rf][0] + bj0;
        f32x4 v1 = acc[rf][1] + bj1;
        int elb = rf * 16 + l4 * 4;
#pragma unroll
        for (int r = 0; r < 4; ++r) {
            unsigned short* op = h + (size_t)(b * EE + elb + r) * DD;
            op[j0]      = (unsigned short)f2bf(v0[r]);
            op[j0 + 16] = (unsigned short)f2bf(v1[r]);
            float s = v0[r] + v1[r];
            float q = v0[r] * v0[r] + v1[r] * v1[r];
            s += __shfl_xor(s, 1); s += __shfl_xor(s, 2); s += __shfl_xor(s, 4); s += __shfl_xor(s, 8);
            q += __shfl_xor(q, 1); q += __shfl_xor(q, 2); q += __shfl_xor(q, 4); q += __shfl_xor(q, 8);
            if (l15 == 0) {
                red[(elb + r) * 4 + w]       = s;
                red[512 + (elb + r) * 4 + w] = q;
            }
        }
    }
    __syncthreads();
    if (t < 128) {
        float s = red[t * 4] + red[t * 4 + 1] + red[t * 4 + 2] + red[t * 4 + 3];
        float q = red[512 + t * 4] + red[512 + t * 4 + 1] + red[512 + t * 4 + 2] + red[512 + t * 4 + 3];
        int slot = b & (NSLOT - 1);
        atomicAdd(&stats2[slot * 256 + t], s);
        atomicAdd(&stats2[slot * 256 + 128 + t], q);
    }
}

// K5: finalize BN2, out = relu(eout + h2*scale + shift); h2 is bf16.
__global__ __launch_bounds__(256)
void k5_final(const unsigned short* __restrict__ h2, const float* __restrict__ eout,
              const float* __restrict__ g2, const float* __restrict__ bt2,
              float* __restrict__ out, const float* __restrict__ stats2)
{
    __shared__ float sc[128];
    __shared__ float sh[128];
    const int t = threadIdx.x;
    if (t < 128) {
        float sm = 0.f, sq = 0.f;
#pragma unroll 8
        for (int sl = 0; sl < NSLOT; ++sl) {
            sm += stats2[sl * 256 + t];
            sq += stats2[sl * 256 + 128 + t];
        }
        const float inv_n = 1.0f / (1024.0f * 128.0f);
        float m    = sm * inv_n;
        float var  = sq * inv_n - m * m;
        float rstd = rsqrtf(var + 1e-5f);
        float s    = rstd * g2[t];
        sc[t] = s;
        sh[t] = bt2[t] - m * s;
    }
    __syncthreads();

    const int total8 = BB * EE * DD / 8;
    for (int i8 = blockIdx.x * blockDim.x + t; i8 < total8; i8 += gridDim.x * blockDim.x) {
        int e = (i8 >> 4) & 127;
        bf16x8 v8 = *(const bf16x8*)(h2 + (size_t)i8 * 8);
        f32x4 u0 = *(const f32x4*)(eout + (size_t)i8 * 8);
        f32x4 u1 = *(const f32x4*)(eout + (size_t)i8 * 8 + 4);
        float s = sc[e], s0 = sh[e];
        f32x4 o0, o1;
#pragma unroll
        for (int i = 0; i < 4; ++i) {
            o0[i] = fmaxf(u0[i] + fmaf(bf2f(v8[i]), s, s0), 0.0f);
            o1[i] = fmaxf(u1[i] + fmaf(bf2f(v8[i + 4]), s, s0), 0.0f);
        }
        *(f32x4*)(out + (size_t)i8 * 8)     = o0;
        *(f32x4*)(out + (size_t)i8 * 8 + 4) = o1;
    }
}

extern "C" void kernel_launch(void* const* d_in, const int* in_sizes, int n_in,
                              void* d_out, int out_size, void* d_ws, size_t ws_size,
                              hipStream_t stream)
{
    const float* gout  = (const float*)d_in[0];
    const float* eout  = (const float*)d_in[1];
    const float* ss    = (const float*)d_in[2];
    const float* es    = (const float*)d_in[3];
    const float* W1    = (const float*)d_in[4];
    const float* b1    = (const float*)d_in[5];
    const float* W2    = (const float*)d_in[6];
    const float* b2    = (const float*)d_in[7];
    const float* g1    = (const float*)d_in[8];
    const float* bt1   = (const float*)d_in[9];
    const float* g2    = (const float*)d_in[10];
    const float* bt2   = (const float*)d_in[11];

    float* stats1 = (float*)d_ws;                       // [64][256]
    float* stats2 = stats1 + NSLOT * 256;               // [64][256]
    unsigned short* h = (unsigned short*)(stats2 + NSLOT * 256);  // [B][E][D] bf16 (h, then h2 in-place)
    float* out    = (float*)d_out;

    hipMemsetAsync((void*)stats1, 0, 2 * NSLOT * 256 * sizeof(float), stream);
    k1_gemm<<<dim3(BB), dim3(512), 0, stream>>>(gout, ss, es, W1, b1, h, stats1);
    k3_gemm<<<dim3(BB), dim3(256), 0, stream>>>(h, W2, b2, g1, bt1, stats1, stats2);
    k5_final<<<dim3(2048), dim3(256), 0, stream>>>(h, eout, g2, bt2, out, stats2);
}

// Round 7
// 272.805 us; speedup vs baseline: 1.2033x; 1.2033x over previous
//
#include <hip/hip_runtime.h>
#include <stdint.h>

#define BB 1024
#define NN 400
#define EE 128
#define DD 128
#define NSLOT 64
#define GTS2 232             // GT row stride in shorts (116 dwords -> 2-way banks, free)
#define KH0 224              // k-half 0: k 0..223 (7 MFMA steps)
#define KH1 192              // k-half 1: k 224..415 (6 steps; zeros past 399)

typedef float f32x4 __attribute__((ext_vector_type(4)));
typedef short bf16x8 __attribute__((ext_vector_type(8)));

__device__ __forceinline__ short f2bf(float f) {
    uint32_t u = __builtin_bit_cast(uint32_t, f);
    u += 0x7fffu + ((u >> 16) & 1u);
    return (short)(u >> 16);
}

__device__ __forceinline__ float bf2f(short s) {
    return __builtin_bit_cast(float, (uint32_t)((uint16_t)s) << 16);
}

__device__ __forceinline__ bf16x8 cvt8(const f32x4 a, const f32x4 b) {
    bf16x8 r;
    r[0] = f2bf(a[0]); r[1] = f2bf(a[1]); r[2] = f2bf(a[2]); r[3] = f2bf(a[3]);
    r[4] = f2bf(b[0]); r[5] = f2bf(b[1]); r[6] = f2bf(b[2]); r[7] = f2bf(b[3]);
    return r;
}

// K0: one-shot convert W1 (32768) and W2 (16384) to bf16 in workspace.
__global__ __launch_bounds__(256)
void k0_cvtw(const float* __restrict__ W1, const float* __restrict__ W2,
             unsigned short* __restrict__ W1b, unsigned short* __restrict__ W2b)
{
    int i = blockIdx.x * 256 + threadIdx.x;
    if (i < 32768) W1b[i] = (unsigned short)f2bf(W1[i]);
    if (i < 16384) W2b[i] = (unsigned short)f2bf(W2[i]);
}

// K1: one 1024-thread block (16 waves) per b. LDS 64KB -> 2 blocks/CU.
//   GT [128][232] staged in two k-halves (mid-loop restage at s==7).
//   Phase 1 barrier-free otherwise: wave w owns 16 P-rows, acc[8] (32 VGPR),
//   2-deep raw-f32 A prefetch ring.
//   Phase 2: P' -> Ps[256][128] swizzled (aliases GT); h = X @ W1bf^T + b1
//   (W1bf from L2); h bf16 + BN1 slot stats.
__global__ __launch_bounds__(1024, 8)
void k1_gemm(const float* __restrict__ gout, const float* __restrict__ ss,
             const float* __restrict__ es, const unsigned short* __restrict__ W1b,
             const float* __restrict__ b1, unsigned short* __restrict__ h,
             float* __restrict__ stats1)
{
    __shared__ short lds[32768];           // 64 KB exactly
    short* GT = lds;                       // [128][232] bf16, phases 0/1
    short* Ps = lds;                       // [256][128] bf16, phase 2 (aliases GT)

    const int b   = blockIdx.x;
    const int t   = threadIdx.x;
    const int w   = t >> 6;                // wave 0..15
    const int l   = t & 63;
    const int l15 = l & 15;
    const int l4  = l >> 4;                // 0..3
    const int kkoff = l4 * 8;

    // ---- pre-issue A ring for K-steps 0,1 (raw f32; cvt deferred) ----
    const int arow = (w & 7) * 16 + l15;
    const float* abase = ((w < 8) ? ss : es) + ((size_t)b * EE + arow) * NN;

    f32x4 pa0 = *(const f32x4*)(abase + kkoff);
    f32x4 pa1 = *(const f32x4*)(abase + kkoff + 4);
    f32x4 pb0 = *(const f32x4*)(abase + 32 + kkoff);
    f32x4 pb1 = *(const f32x4*)(abase + 32 + kkoff + 4);

    // ---- GT staging (k-quads packed, b64 writes; 1024 threads) ----
    const float* gb = gout + (size_t)b * NN * DD + (t & 127);
    auto stage = [&](int koff, int nq) {
        const int qb = t >> 7;             // 0..7
        short* row = &GT[(t & 127) * GTS2];
        for (int q = qb; q < nq; q += 8) {
            int kg = koff + 4 * q;
            float v0 = (kg     < NN) ? gb[(size_t)(kg)     * DD] : 0.f;
            float v1 = (kg + 1 < NN) ? gb[(size_t)(kg + 1) * DD] : 0.f;
            float v2 = (kg + 2 < NN) ? gb[(size_t)(kg + 2) * DD] : 0.f;
            float v3 = (kg + 3 < NN) ? gb[(size_t)(kg + 3) * DD] : 0.f;
            uint32_t lo = (uint32_t)(uint16_t)f2bf(v0) | ((uint32_t)(uint16_t)f2bf(v1) << 16);
            uint32_t hi = (uint32_t)(uint16_t)f2bf(v2) | ((uint32_t)(uint16_t)f2bf(v3) << 16);
            *(uint64_t*)&row[4 * q] = ((uint64_t)hi << 32) | lo;
        }
    };

    stage(0, KH0 / 4);                     // k 0..223
    __syncthreads();

    // ---- phase 1: P(16 rows x 128 d per wave) ----
    f32x4 acc[8];
#pragma unroll
    for (int cf = 0; cf < 8; ++cf) acc[cf] = f32x4{0.f, 0.f, 0.f, 0.f};

#pragma unroll
    for (int s = 0; s < 13; ++s) {
        if (s == 7) {
            __syncthreads();               // all reads of half-0 done
            stage(KH0, KH1 / 4);           // k 224..415 (zeros past 399)
            __syncthreads();
        }
        bf16x8 a = cvt8(pa0, pa1);         // loads from 2 iterations ago
        pa0 = pb0; pa1 = pb1;
        const int sn = s + 2;
        if (sn < 12) {
            pb0 = *(const f32x4*)(abase + sn * 32 + kkoff);
            pb1 = *(const f32x4*)(abase + sn * 32 + kkoff + 4);
        } else if (sn == 12) {
            int kk = 384 + kkoff;
            pb0 = f32x4{0.f, 0.f, 0.f, 0.f};
            pb1 = f32x4{0.f, 0.f, 0.f, 0.f};
            if (kk < NN)     pb0 = *(const f32x4*)(abase + kk);
            if (kk + 4 < NN) pb1 = *(const f32x4*)(abase + kk + 4);
        }
        const int k0 = (s < 7 ? s * 32 : (s - 7) * 32) + kkoff;
#pragma unroll
        for (int cf = 0; cf < 8; ++cf) {
            bf16x8 gf = *(const bf16x8*)&GT[(cf * 16 + l15) * GTS2 + k0];
            acc[cf] = __builtin_amdgcn_mfma_f32_16x16x32_bf16(a, gf, acc[cf], 0, 0, 0);
        }
    }
    __syncthreads();                       // GT dead; Ps live

    // ---- phase 2a: write P' swizzled into Ps[256][128] ----
#pragma unroll
    for (int cf = 0; cf < 8; ++cf)
#pragma unroll
        for (int r = 0; r < 4; ++r) {
            int row = w * 16 + l4 * 4 + r;         // 0..255 (S rows, then T rows)
            int col = cf * 16 + l15;
            Ps[row * 128 + (((col >> 3) ^ (row & 7)) << 3) + (col & 7)] = f2bf(acc[cf][r]);
        }
    __syncthreads();

    // ---- phase 2b: h(16 e-rows x 64 j per wave) = X @ W1^T (W1bf from L2) ----
    const int mt = w >> 1;                 // 0..7
    const int jh = w & 1;
    f32x4 acc2[4];
#pragma unroll
    for (int cf = 0; cf < 4; ++cf) acc2[cf] = f32x4{0.f, 0.f, 0.f, 0.f};

#pragma unroll
    for (int kf = 0; kf < 8; ++kf) {
        int roff = (kf >= 4) ? 128 : 0;
        int kcol = (kf & 3) * 32 + l4 * 8;
        int row  = roff + mt * 16 + l15;
        int cb   = kcol >> 3;
        bf16x8 xf = *(const bf16x8*)&Ps[row * 128 + ((cb ^ (row & 7)) << 3)];
#pragma unroll
        for (int cf = 0; cf < 4; ++cf) {
            int j = jh * 64 + cf * 16 + l15;
            bf16x8 wf = *(const bf16x8*)&W1b[(size_t)j * 256 + kf * 32 + l4 * 8];
            acc2[cf] = __builtin_amdgcn_mfma_f32_16x16x32_bf16(xf, wf, acc2[cf], 0, 0, 0);
        }
    }
    __syncthreads();                       // Ps dead; red live

    // ---- phase 2c: bias, store h (bf16), BN1 stats ----
    float* red = (float*)lds;
    float s_r[4] = {0.f, 0.f, 0.f, 0.f};
    float q_r[4] = {0.f, 0.f, 0.f, 0.f};
#pragma unroll
    for (int cf = 0; cf < 4; ++cf) {
        float bv = b1[jh * 64 + cf * 16 + l15];
        f32x4 v = acc2[cf] + bv;
#pragma unroll
        for (int r = 0; r < 4; ++r) {
            int e = mt * 16 + l4 * 4 + r;
            h[((size_t)b * EE + e) * DD + jh * 64 + cf * 16 + l15] = (unsigned short)f2bf(v[r]);
            s_r[r] += v[r];
            q_r[r] += v[r] * v[r];
        }
    }
#pragma unroll
    for (int r = 0; r < 4; ++r) {
        float s = s_r[r], q = q_r[r];
        s += __shfl_xor(s, 1); s += __shfl_xor(s, 2); s += __shfl_xor(s, 4); s += __shfl_xor(s, 8);
        q += __shfl_xor(q, 1); q += __shfl_xor(q, 2); q += __shfl_xor(q, 4); q += __shfl_xor(q, 8);
        if (l15 == 0) {
            int e = mt * 16 + l4 * 4 + r;
            red[(e << 1) | jh]         = s;
            red[256 + ((e << 1) | jh)] = q;
        }
    }
    __syncthreads();
    if (t < 128) {
        float s = red[2 * t] + red[2 * t + 1];
        float q = red[256 + 2 * t] + red[256 + 2 * t + 1];
        int slot = b & (NSLOT - 1);
        atomicAdd(&stats1[slot * 256 + t], s);
        atomicAdd(&stats1[slot * 256 + 128 + t], q);
    }
}

// K3: per b: finalize BN1, normalize+relu h(bf16) -> bf16 LDS,
// h2 = X @ W2bf^T + b2 -> IN-PLACE over h (bf16), BN2 stats.
__global__ __launch_bounds__(256, 4)
void k3_gemm(unsigned short* h, const unsigned short* __restrict__ W2b,
             const float* __restrict__ b2, const float* __restrict__ g1,
             const float* __restrict__ bt1,
             const float* __restrict__ stats1, float* __restrict__ stats2)
{
    __shared__ short Xs[128 * 128];
    __shared__ float sc[128];
    __shared__ float sh[128];
    const int b   = blockIdx.x;
    const int t   = threadIdx.x;
    const int w   = t >> 6;
    const int l15 = t & 15;
    const int l4  = (t >> 4) & 3;

    if (t < 128) {
        float sm = 0.f, sq = 0.f;
#pragma unroll 8
        for (int sl = 0; sl < NSLOT; ++sl) {
            sm += stats1[sl * 256 + t];
            sq += stats1[sl * 256 + 128 + t];
        }
        const float inv_n = 1.0f / (1024.0f * 128.0f);
        float m    = sm * inv_n;
        float var  = sq * inv_n - m * m;
        float rstd = rsqrtf(var + 1e-5f);
        float s    = rstd * g1[t];
        sc[t] = s;
        sh[t] = bt1[t] - m * s;
    }
    __syncthreads();

    {
        const int c8 = t & 15;
        const int eb = t >> 4;
#pragma unroll
        for (int p = 0; p < 8; ++p) {
            int e = eb + 16 * p;
            bf16x8 v8 = *(const bf16x8*)&h[((size_t)b * EE + e) * DD + c8 * 8];
            float s = sc[e], s0 = sh[e];
            bf16x8 o;
#pragma unroll
            for (int i = 0; i < 8; ++i)
                o[i] = f2bf(fmaxf(fmaf(bf2f(v8[i]), s, s0), 0.0f));
            *(bf16x8*)&Xs[e * 128 + ((c8 ^ (e & 7)) << 3)] = o;
        }
    }
    __syncthreads();

    f32x4 acc[8][2];
#pragma unroll
    for (int i = 0; i < 8; ++i) {
        acc[i][0] = f32x4{0.f, 0.f, 0.f, 0.f};
        acc[i][1] = f32x4{0.f, 0.f, 0.f, 0.f};
    }
#pragma unroll
    for (int kf = 0; kf < 4; ++kf) {
        const int k0 = kf * 32;
        const int cb = (k0 >> 3) + l4;
        bf16x8 af[8];
#pragma unroll
        for (int rf = 0; rf < 8; ++rf) {
            int row = rf * 16 + l15;
            af[rf] = *(const bf16x8*)&Xs[row * 128 + ((cb ^ (row & 7)) * 8)];
        }
#pragma unroll
        for (int cf = 0; cf < 2; ++cf) {
            int j = w * 32 + cf * 16 + l15;
            bf16x8 bfr = *(const bf16x8*)&W2b[(size_t)j * 128 + k0 + l4 * 8];
#pragma unroll
            for (int rf = 0; rf < 8; ++rf)
                acc[rf][cf] = __builtin_amdgcn_mfma_f32_16x16x32_bf16(af[rf], bfr, acc[rf][cf], 0, 0, 0);
        }
    }

    __syncthreads();
    float* red = (float*)Xs;
    const float bj0 = b2[w * 32 + l15];
    const float bj1 = b2[w * 32 + 16 + l15];
    const int j0 = w * 32 + l15;
#pragma unroll
    for (int rf = 0; rf < 8; ++rf) {
        f32x4 v0 = acc[rf][0] + bj0;
        f32x4 v1 = acc[rf][1] + bj1;
        int elb = rf * 16 + l4 * 4;
#pragma unroll
        for (int r = 0; r < 4; ++r) {
            unsigned short* op = h + (size_t)(b * EE + elb + r) * DD;
            op[j0]      = (unsigned short)f2bf(v0[r]);
            op[j0 + 16] = (unsigned short)f2bf(v1[r]);
            float s = v0[r] + v1[r];
            float q = v0[r] * v0[r] + v1[r] * v1[r];
            s += __shfl_xor(s, 1); s += __shfl_xor(s, 2); s += __shfl_xor(s, 4); s += __shfl_xor(s, 8);
            q += __shfl_xor(q, 1); q += __shfl_xor(q, 2); q += __shfl_xor(q, 4); q += __shfl_xor(q, 8);
            if (l15 == 0) {
                red[(elb + r) * 4 + w]       = s;
                red[512 + (elb + r) * 4 + w] = q;
            }
        }
    }
    __syncthreads();
    if (t < 128) {
        float s = red[t * 4] + red[t * 4 + 1] + red[t * 4 + 2] + red[t * 4 + 3];
        float q = red[512 + t * 4] + red[512 + t * 4 + 1] + red[512 + t * 4 + 2] + red[512 + t * 4 + 3];
        int slot = b & (NSLOT - 1);
        atomicAdd(&stats2[slot * 256 + t], s);
        atomicAdd(&stats2[slot * 256 + 128 + t], q);
    }
}

// K5: finalize BN2, out = relu(eout + h2*scale + shift); h2 is bf16.
__global__ __launch_bounds__(256)
void k5_final(const unsigned short* __restrict__ h2, const float* __restrict__ eout,
              const float* __restrict__ g2, const float* __restrict__ bt2,
              float* __restrict__ out, const float* __restrict__ stats2)
{
    __shared__ float sc[128];
    __shared__ float sh[128];
    const int t = threadIdx.x;
    if (t < 128) {
        float sm = 0.f, sq = 0.f;
#pragma unroll 8
        for (int sl = 0; sl < NSLOT; ++sl) {
            sm += stats2[sl * 256 + t];
            sq += stats2[sl * 256 + 128 + t];
        }
        const float inv_n = 1.0f / (1024.0f * 128.0f);
        float m    = sm * inv_n;
        float var  = sq * inv_n - m * m;
        float rstd = rsqrtf(var + 1e-5f);
        float s    = rstd * g2[t];
        sc[t] = s;
        sh[t] = bt2[t] - m * s;
    }
    __syncthreads();

    const int total8 = BB * EE * DD / 8;
    for (int i8 = blockIdx.x * blockDim.x + t; i8 < total8; i8 += gridDim.x * blockDim.x) {
        int e = (i8 >> 4) & 127;
        bf16x8 v8 = *(const bf16x8*)(h2 + (size_t)i8 * 8);
        f32x4 u0 = *(const f32x4*)(eout + (size_t)i8 * 8);
        f32x4 u1 = *(const f32x4*)(eout + (size_t)i8 * 8 + 4);
        float s = sc[e], s0 = sh[e];
        f32x4 o0, o1;
#pragma unroll
        for (int i = 0; i < 4; ++i) {
            o0[i] = fmaxf(u0[i] + fmaf(bf2f(v8[i]), s, s0), 0.0f);
            o1[i] = fmaxf(u1[i] + fmaf(bf2f(v8[i + 4]), s, s0), 0.0f);
        }
        *(f32x4*)(out + (size_t)i8 * 8)     = o0;
        *(f32x4*)(out + (size_t)i8 * 8 + 4) = o1;
    }
}

extern "C" void kernel_launch(void* const* d_in, const int* in_sizes, int n_in,
                              void* d_out, int out_size, void* d_ws, size_t ws_size,
                              hipStream_t stream)
{
    const float* gout  = (const float*)d_in[0];
    const float* eout  = (const float*)d_in[1];
    const float* ss    = (const float*)d_in[2];
    const float* es    = (const float*)d_in[3];
    const float* W1    = (const float*)d_in[4];
    const float* b1    = (const float*)d_in[5];
    const float* W2    = (const float*)d_in[6];
    const float* b2    = (const float*)d_in[7];
    const float* g1    = (const float*)d_in[8];
    const float* bt1   = (const float*)d_in[9];
    const float* g2    = (const float*)d_in[10];
    const float* bt2   = (const float*)d_in[11];

    float* stats1 = (float*)d_ws;                              // [64][256]
    float* stats2 = stats1 + NSLOT * 256;                      // [64][256]
    unsigned short* W1b = (unsigned short*)(stats2 + NSLOT * 256);  // 32768 bf16
    unsigned short* W2b = W1b + 32768;                         // 16384 bf16
    unsigned short* h   = W2b + 16384;                         // [B][E][D] bf16 (h, then h2 in-place)
    float* out    = (float*)d_out;

    hipMemsetAsync((void*)stats1, 0, 2 * NSLOT * 256 * sizeof(float), stream);
    k0_cvtw<<<dim3(128), dim3(256), 0, stream>>>(W1, W2, W1b, W2b);
    k1_gemm<<<dim3(BB), dim3(1024), 0, stream>>>(gout, ss, es, W1b, b1, h, stats1);
    k3_gemm<<<dim3(BB), dim3(256), 0, stream>>>(h, W2b, b2, g1, bt1, stats1, stats2);
    k5_final<<<dim3(2048), dim3(256), 0, stream>>>(h, eout, g2, bt2, out, stats2);
}

// Round 8
// 262.765 us; speedup vs baseline: 1.2493x; 1.0382x over previous
//
#include <hip/hip_runtime.h>
#include <stdint.h>

#define BB 1024
#define NN 400
#define EE 128
#define DD 128
#define NSLOT 64
#define GTS 424              // GT row stride in shorts (848B rows; 212 dwords -> bank spread)

typedef float f32x4 __attribute__((ext_vector_type(4)));
typedef short bf16x8 __attribute__((ext_vector_type(8)));

__device__ __forceinline__ short f2bf(float f) {
    uint32_t u = __builtin_bit_cast(uint32_t, f);
    u += 0x7fffu + ((u >> 16) & 1u);
    return (short)(u >> 16);
}

__device__ __forceinline__ float bf2f(short s) {
    return __builtin_bit_cast(float, (uint32_t)((uint16_t)s) << 16);
}

__device__ __forceinline__ bf16x8 cvt8(const f32x4 a, const f32x4 b) {
    bf16x8 r;
    r[0] = f2bf(a[0]); r[1] = f2bf(a[1]); r[2] = f2bf(a[2]); r[3] = f2bf(a[3]);
    r[4] = f2bf(b[0]); r[5] = f2bf(b[1]); r[6] = f2bf(b[2]); r[7] = f2bf(b[3]);
    return r;
}

// K0: one-shot convert W1 (32768) and W2 (16384) to bf16 in workspace.
__global__ __launch_bounds__(256)
void k0_cvtw(const float* __restrict__ W1, const float* __restrict__ W2,
             unsigned short* __restrict__ W1b, unsigned short* __restrict__ W2b)
{
    int i = blockIdx.x * 256 + threadIdx.x;
    if (i < 32768) W1b[i] = (unsigned short)f2bf(W1[i]);
    if (i < 16384) W2b[i] = (unsigned short)f2bf(W2[i]);
}

// K1a: PURE stage-1 GEMM. One 1024-thread block per b.
//   Stage GT[b] (bf16 [128][424]) once; barrier; 13-step barrier-free K-loop
//   (2-deep raw-f32 A ring, 8 ds_read_b128 + 8 MFMA per wave-step);
//   barrier; P' -> LDS swizzled; barrier; linear b128 stream-out of the
//   64KB swizzled P image to global (consumed by k1b as a linear copy-in).
__global__ __launch_bounds__(1024, 1)
void k1a_gemm(const float* __restrict__ gout, const float* __restrict__ ss,
              const float* __restrict__ es, unsigned short* __restrict__ Pg)
{
    __shared__ short lds[54272];           // 106 KB
    short* GT = lds;                       // [128][424] bf16
    short* Pl = lds;                       // [256][128] bf16 swizzled (aliases GT)

    const int b   = blockIdx.x;
    const int t   = threadIdx.x;
    const int w   = t >> 6;                // wave 0..15
    const int l   = t & 63;
    const int l15 = l & 15;
    const int l4  = l >> 4;                // 0..3
    const int kkoff = l4 * 8;

    // pre-issue A ring for K-steps 0,1 (raw f32; cvt deferred 2 iters)
    const int arow = (w & 7) * 16 + l15;
    const float* abase = ((w < 8) ? ss : es) + ((size_t)b * EE + arow) * NN;

    f32x4 pa0 = *(const f32x4*)(abase + kkoff);
    f32x4 pa1 = *(const f32x4*)(abase + kkoff + 4);
    f32x4 pb0 = *(const f32x4*)(abase + 32 + kkoff);
    f32x4 pb1 = *(const f32x4*)(abase + 32 + kkoff + 4);

    // stage GT (full 400 k, zero-padded to 424; k-quads packed, b64 writes)
    {
        const float* gb = gout + (size_t)b * NN * DD + (t & 127);
        const int qb = t >> 7;             // 0..7
        short* row = &GT[(t & 127) * GTS];
        for (int q = qb; q < 106; q += 8) {
            int kg = 4 * q;
            float v0 = (kg     < NN) ? gb[(size_t)(kg)     * DD] : 0.f;
            float v1 = (kg + 1 < NN) ? gb[(size_t)(kg + 1) * DD] : 0.f;
            float v2 = (kg + 2 < NN) ? gb[(size_t)(kg + 2) * DD] : 0.f;
            float v3 = (kg + 3 < NN) ? gb[(size_t)(kg + 3) * DD] : 0.f;
            uint32_t lo = (uint32_t)(uint16_t)f2bf(v0) | ((uint32_t)(uint16_t)f2bf(v1) << 16);
            uint32_t hi = (uint32_t)(uint16_t)f2bf(v2) | ((uint32_t)(uint16_t)f2bf(v3) << 16);
            *(uint64_t*)&row[4 * q] = ((uint64_t)hi << 32) | lo;
        }
    }
    __syncthreads();

    // K-loop: P(16 rows x 128 d per wave), barrier-free
    f32x4 acc[8];
#pragma unroll
    for (int cf = 0; cf < 8; ++cf) acc[cf] = f32x4{0.f, 0.f, 0.f, 0.f};

#pragma unroll
    for (int s = 0; s < 13; ++s) {
        bf16x8 a = cvt8(pa0, pa1);
        pa0 = pb0; pa1 = pb1;
        const int sn = s + 2;
        if (sn < 12) {
            pb0 = *(const f32x4*)(abase + sn * 32 + kkoff);
            pb1 = *(const f32x4*)(abase + sn * 32 + kkoff + 4);
        } else if (sn == 12) {
            int kk = 384 + kkoff;
            pb0 = f32x4{0.f, 0.f, 0.f, 0.f};
            pb1 = f32x4{0.f, 0.f, 0.f, 0.f};
            if (kk < NN)     pb0 = *(const f32x4*)(abase + kk);
            if (kk + 4 < NN) pb1 = *(const f32x4*)(abase + kk + 4);
        }
        const int k0 = s * 32 + kkoff;
#pragma unroll
        for (int cf = 0; cf < 8; ++cf) {
            bf16x8 gf = *(const bf16x8*)&GT[(cf * 16 + l15) * GTS + k0];
            acc[cf] = __builtin_amdgcn_mfma_f32_16x16x32_bf16(a, gf, acc[cf], 0, 0, 0);
        }
    }
    __syncthreads();                       // GT dead; Pl live

    // P' -> Pl swizzled: elem(row,col) at row*128 + ((col>>3 ^ row&7)<<3) + col&7
#pragma unroll
    for (int cf = 0; cf < 8; ++cf)
#pragma unroll
        for (int r = 0; r < 4; ++r) {
            int row = w * 16 + l4 * 4 + r;         // 0..255 (S rows, then T rows)
            int col = cf * 16 + l15;
            Pl[row * 128 + (((col >> 3) ^ (row & 7)) << 3) + (col & 7)] = f2bf(acc[cf][r]);
        }
    __syncthreads();

    // stream the 64KB swizzled image out linearly (b128, fully coalesced)
    unsigned short* pg = Pg + (size_t)b * 32768;
#pragma unroll
    for (int i = 0; i < 4; ++i) {
        int idx = i * 1024 + t;                    // 16B-chunk id, 4096 total
        bf16x8 v = *(const bf16x8*)&lds[idx * 8];
        *(bf16x8*)&pg[idx * 8] = v;
    }
}

// K1b: per b: copy P[b] (64KB, already-swizzled image) into LDS linearly,
// h = X @ W1b^T + b1 (X = [P_S | P_T] along k), write h bf16, BN1 slot stats.
__global__ __launch_bounds__(256, 2)
void k1b_stage2(const unsigned short* __restrict__ Pg,
                const unsigned short* __restrict__ W1b,
                const float* __restrict__ b1, unsigned short* __restrict__ h,
                float* __restrict__ stats1)
{
    __shared__ short Ps[32768];            // 64KB
    const int b   = blockIdx.x;
    const int t   = threadIdx.x;
    const int w   = t >> 6;
    const int l15 = t & 15;
    const int l4  = (t >> 4) & 3;

    const unsigned short* pg = Pg + (size_t)b * 32768;
#pragma unroll
    for (int i = 0; i < 16; ++i) {
        int idx = i * 256 + t;                     // 16B-chunk id
        bf16x8 v = *(const bf16x8*)&pg[idx * 8];
        *(bf16x8*)&Ps[idx * 8] = v;
    }
    __syncthreads();

    f32x4 acc[8][2];
#pragma unroll
    for (int i = 0; i < 8; ++i) {
        acc[i][0] = f32x4{0.f, 0.f, 0.f, 0.f};
        acc[i][1] = f32x4{0.f, 0.f, 0.f, 0.f};
    }
#pragma unroll
    for (int kf = 0; kf < 8; ++kf) {
        const int roff = (kf >= 4) ? 128 : 0;      // k<128: P_S rows; k>=128: P_T rows
        const int cb   = (kf & 3) * 4 + l4;
        bf16x8 af[8];
#pragma unroll
        for (int rf = 0; rf < 8; ++rf) {
            int row = roff + rf * 16 + l15;
            af[rf] = *(const bf16x8*)&Ps[row * 128 + ((cb ^ (row & 7)) << 3)];
        }
#pragma unroll
        for (int cf = 0; cf < 2; ++cf) {
            int j = w * 32 + cf * 16 + l15;
            bf16x8 wf = *(const bf16x8*)&W1b[(size_t)j * 256 + kf * 32 + l4 * 8];
#pragma unroll
            for (int rf = 0; rf < 8; ++rf)
                acc[rf][cf] = __builtin_amdgcn_mfma_f32_16x16x32_bf16(af[rf], wf, acc[rf][cf], 0, 0, 0);
        }
    }

    __syncthreads();                       // Ps dead; red live
    float* red = (float*)Ps;
    const float bj0 = b1[w * 32 + l15];
    const float bj1 = b1[w * 32 + 16 + l15];
    const int j0 = w * 32 + l15;
#pragma unroll
    for (int rf = 0; rf < 8; ++rf) {
        f32x4 v0 = acc[rf][0] + bj0;
        f32x4 v1 = acc[rf][1] + bj1;
        int elb = rf * 16 + l4 * 4;
#pragma unroll
        for (int r = 0; r < 4; ++r) {
            unsigned short* hp = h + (size_t)(b * EE + elb + r) * DD;
            hp[j0]      = (unsigned short)f2bf(v0[r]);
            hp[j0 + 16] = (unsigned short)f2bf(v1[r]);
            float s = v0[r] + v1[r];
            float q = v0[r] * v0[r] + v1[r] * v1[r];
            s += __shfl_xor(s, 1); s += __shfl_xor(s, 2); s += __shfl_xor(s, 4); s += __shfl_xor(s, 8);
            q += __shfl_xor(q, 1); q += __shfl_xor(q, 2); q += __shfl_xor(q, 4); q += __shfl_xor(q, 8);
            if (l15 == 0) {
                red[(elb + r) * 4 + w]       = s;
                red[512 + (elb + r) * 4 + w] = q;
            }
        }
    }
    __syncthreads();
    if (t < 128) {
        float s = red[t * 4] + red[t * 4 + 1] + red[t * 4 + 2] + red[t * 4 + 3];
        float q = red[512 + t * 4] + red[512 + t * 4 + 1] + red[512 + t * 4 + 2] + red[512 + t * 4 + 3];
        int slot = b & (NSLOT - 1);
        atomicAdd(&stats1[slot * 256 + t], s);
        atomicAdd(&stats1[slot * 256 + 128 + t], q);
    }
}

// K3: per b: finalize BN1, normalize+relu h(bf16) -> bf16 LDS,
// h2 = X @ W2b^T + b2 -> IN-PLACE over h (bf16), BN2 stats.
__global__ __launch_bounds__(256, 4)
void k3_gemm(unsigned short* h, const unsigned short* __restrict__ W2b,
             const float* __restrict__ b2, const float* __restrict__ g1,
             const float* __restrict__ bt1,
             const float* __restrict__ stats1, float* __restrict__ stats2)
{
    __shared__ short Xs[128 * 128];
    __shared__ float sc[128];
    __shared__ float sh[128];
    const int b   = blockIdx.x;
    const int t   = threadIdx.x;
    const int w   = t >> 6;
    const int l15 = t & 15;
    const int l4  = (t >> 4) & 3;

    if (t < 128) {
        float sm = 0.f, sq = 0.f;
#pragma unroll 8
        for (int sl = 0; sl < NSLOT; ++sl) {
            sm += stats1[sl * 256 + t];
            sq += stats1[sl * 256 + 128 + t];
        }
        const float inv_n = 1.0f / (1024.0f * 128.0f);
        float m    = sm * inv_n;
        float var  = sq * inv_n - m * m;
        float rstd = rsqrtf(var + 1e-5f);
        float s    = rstd * g1[t];
        sc[t] = s;
        sh[t] = bt1[t] - m * s;
    }
    __syncthreads();

    {
        const int c8 = t & 15;
        const int eb = t >> 4;
#pragma unroll
        for (int p = 0; p < 8; ++p) {
            int e = eb + 16 * p;
            bf16x8 v8 = *(const bf16x8*)&h[((size_t)b * EE + e) * DD + c8 * 8];
            float s = sc[e], s0 = sh[e];
            bf16x8 o;
#pragma unroll
            for (int i = 0; i < 8; ++i)
                o[i] = f2bf(fmaxf(fmaf(bf2f(v8[i]), s, s0), 0.0f));
            *(bf16x8*)&Xs[e * 128 + ((c8 ^ (e & 7)) << 3)] = o;
        }
    }
    __syncthreads();

    f32x4 acc[8][2];
#pragma unroll
    for (int i = 0; i < 8; ++i) {
        acc[i][0] = f32x4{0.f, 0.f, 0.f, 0.f};
        acc[i][1] = f32x4{0.f, 0.f, 0.f, 0.f};
    }
#pragma unroll
    for (int kf = 0; kf < 4; ++kf) {
        const int k0 = kf * 32;
        const int cb = (k0 >> 3) + l4;
        bf16x8 af[8];
#pragma unroll
        for (int rf = 0; rf < 8; ++rf) {
            int row = rf * 16 + l15;
            af[rf] = *(const bf16x8*)&Xs[row * 128 + ((cb ^ (row & 7)) * 8)];
        }
#pragma unroll
        for (int cf = 0; cf < 2; ++cf) {
            int j = w * 32 + cf * 16 + l15;
            bf16x8 bfr = *(const bf16x8*)&W2b[(size_t)j * 128 + k0 + l4 * 8];
#pragma unroll
            for (int rf = 0; rf < 8; ++rf)
                acc[rf][cf] = __builtin_amdgcn_mfma_f32_16x16x32_bf16(af[rf], bfr, acc[rf][cf], 0, 0, 0);
        }
    }

    __syncthreads();
    float* red = (float*)Xs;
    const float bj0 = b2[w * 32 + l15];
    const float bj1 = b2[w * 32 + 16 + l15];
    const int j0 = w * 32 + l15;
#pragma unroll
    for (int rf = 0; rf < 8; ++rf) {
        f32x4 v0 = acc[rf][0] + bj0;
        f32x4 v1 = acc[rf][1] + bj1;
        int elb = rf * 16 + l4 * 4;
#pragma unroll
        for (int r = 0; r < 4; ++r) {
            unsigned short* op = h + (size_t)(b * EE + elb + r) * DD;
            op[j0]      = (unsigned short)f2bf(v0[r]);
            op[j0 + 16] = (unsigned short)f2bf(v1[r]);
            float s = v0[r] + v1[r];
            float q = v0[r] * v0[r] + v1[r] * v1[r];
            s += __shfl_xor(s, 1); s += __shfl_xor(s, 2); s += __shfl_xor(s, 4); s += __shfl_xor(s, 8);
            q += __shfl_xor(q, 1); q += __shfl_xor(q, 2); q += __shfl_xor(q, 4); q += __shfl_xor(q, 8);
            if (l15 == 0) {
                red[(elb + r) * 4 + w]       = s;
                red[512 + (elb + r) * 4 + w] = q;
            }
        }
    }
    __syncthreads();
    if (t < 128) {
        float s = red[t * 4] + red[t * 4 + 1] + red[t * 4 + 2] + red[t * 4 + 3];
        float q = red[512 + t * 4] + red[512 + t * 4 + 1] + red[512 + t * 4 + 2] + red[512 + t * 4 + 3];
        int slot = b & (NSLOT - 1);
        atomicAdd(&stats2[slot * 256 + t], s);
        atomicAdd(&stats2[slot * 256 + 128 + t], q);
    }
}

// K5: finalize BN2, out = relu(eout + h2*scale + shift); h2 is bf16.
__global__ __launch_bounds__(256)
void k5_final(const unsigned short* __restrict__ h2, const float* __restrict__ eout,
              const float* __restrict__ g2, const float* __restrict__ bt2,
              float* __restrict__ out, const float* __restrict__ stats2)
{
    __shared__ float sc[128];
    __shared__ float sh[128];
    const int t = threadIdx.x;
    if (t < 128) {
        float sm = 0.f, sq = 0.f;
#pragma unroll 8
        for (int sl = 0; sl < NSLOT; ++sl) {
            sm += stats2[sl * 256 + t];
            sq += stats2[sl * 256 + 128 + t];
        }
        const float inv_n = 1.0f / (1024.0f * 128.0f);
        float m    = sm * inv_n;
        float var  = sq * inv_n - m * m;
        float rstd = rsqrtf(var + 1e-5f);
        float s    = rstd * g2[t];
        sc[t] = s;
        sh[t] = bt2[t] - m * s;
    }
    __syncthreads();

    const int total8 = BB * EE * DD / 8;
    for (int i8 = blockIdx.x * blockDim.x + t; i8 < total8; i8 += gridDim.x * blockDim.x) {
        int e = (i8 >> 4) & 127;
        bf16x8 v8 = *(const bf16x8*)(h2 + (size_t)i8 * 8);
        f32x4 u0 = *(const f32x4*)(eout + (size_t)i8 * 8);
        f32x4 u1 = *(const f32x4*)(eout + (size_t)i8 * 8 + 4);
        float s = sc[e], s0 = sh[e];
        f32x4 o0, o1;
#pragma unroll
        for (int i = 0; i < 4; ++i) {
            o0[i] = fmaxf(u0[i] + fmaf(bf2f(v8[i]), s, s0), 0.0f);
            o1[i] = fmaxf(u1[i] + fmaf(bf2f(v8[i + 4]), s, s0), 0.0f);
        }
        *(f32x4*)(out + (size_t)i8 * 8)     = o0;
        *(f32x4*)(out + (size_t)i8 * 8 + 4) = o1;
    }
}

extern "C" void kernel_launch(void* const* d_in, const int* in_sizes, int n_in,
                              void* d_out, int out_size, void* d_ws, size_t ws_size,
                              hipStream_t stream)
{
    const float* gout  = (const float*)d_in[0];
    const float* eout  = (const float*)d_in[1];
    const float* ss    = (const float*)d_in[2];
    const float* es    = (const float*)d_in[3];
    const float* W1    = (const float*)d_in[4];
    const float* b1    = (const float*)d_in[5];
    const float* W2    = (const float*)d_in[6];
    const float* b2    = (const float*)d_in[7];
    const float* g1    = (const float*)d_in[8];
    const float* bt1   = (const float*)d_in[9];
    const float* g2    = (const float*)d_in[10];
    const float* bt2   = (const float*)d_in[11];

    float* stats1 = (float*)d_ws;                              // [64][256]
    float* stats2 = stats1 + NSLOT * 256;                      // [64][256]
    unsigned short* W1b = (unsigned short*)(stats2 + NSLOT * 256);  // 32768 bf16
    unsigned short* W2b = W1b + 32768;                         // 16384 bf16
    unsigned short* h   = W2b + 16384;                         // [B][E][D] bf16 (h, then h2 in-place)
    unsigned short* Pg  = (unsigned short*)d_out;              // [B][256][128] bf16 swizzled (64MB <= out 67MB)
    float* out    = (float*)d_out;

    hipMemsetAsync((void*)stats1, 0, 2 * NSLOT * 256 * sizeof(float), stream);
    k0_cvtw<<<dim3(128), dim3(256), 0, stream>>>(W1, W2, W1b, W2b);
    k1a_gemm<<<dim3(BB), dim3(1024), 0, stream>>>(gout, ss, es, Pg);
    k1b_stage2<<<dim3(BB), dim3(256), 0, stream>>>(Pg, W1b, b1, h, stats1);
    k3_gemm<<<dim3(BB), dim3(256), 0, stream>>>(h, W2b, b2, g1, bt1, stats1, stats2);
    k5_final<<<dim3(2048), dim3(256), 0, stream>>>(h, eout, g2, bt2, out, stats2);
}